// Round 1
// baseline (331.585 us; speedup 1.0000x reference)
//
#include <hip/hip_runtime.h>
#include <hip/hip_bf16.h>

// ElasticMLP fused: 8 layers, H=128, B=262144, relu each layer, skip(+x) for l>0.
//
// Round-3 structure:
//  - A-fragments (W) loaded DIRECTLY from global in fragment layout (per-lane
//    addresses). W is 32 KB/layer bf16, shared by all blocks -> L1/L2 resident.
//    This removes W from LDS: no staging writes, no af ds_reads, and the
//    LDS pipe (previously the busiest: ~4.6k cyc/CU/layer) is halved.
//  - hs double-buffered -> ONE __syncthreads per layer (was 2). Layer l reads
//    hs[l&1], writes hs[(l&1)^1]; the buffer swap separates the RAW/WAR pairs.
//  - Next-layer af[mi][k] reloaded immediately after its last use (k-step k),
//    so global-load latency hides under the remaining MFMAs + epilogue.
// MFMA roles as round-2: A = W (m = neuron), B = h (n = batch); C gives each
// lane 4 consecutive neurons of one batch row -> b64 LDS writebacks, dwordx4
// x-loads/out-stores. Bias folded into acc init.

typedef __bf16 bf16_t;
typedef __bf16 bf16x8 __attribute__((ext_vector_type(8)));
typedef __bf16 bf16x4 __attribute__((ext_vector_type(4)));
typedef float floatx4 __attribute__((ext_vector_type(4)));

#define HID 128
#define NLAYERS 8
#define TM 128          // batch rows per block
#define LDH 136         // LDS row stride (bf16 elems): 272B keeps 16B alignment,
                        // 2-way-max bank aliasing on b128 reads (free on CDNA4)

__global__ __launch_bounds__(256) void wconv_kernel(const float* __restrict__ w,
                                                    bf16_t* __restrict__ wb) {
    int i = (blockIdx.x * 256 + threadIdx.x) * 4;   // 131072 elems / 4 => 128 blocks
    floatx4 v = *(const floatx4*)&w[i];
    bf16x4 o = { (bf16_t)v[0], (bf16_t)v[1], (bf16_t)v[2], (bf16_t)v[3] };
    *(bf16x4*)&wb[i] = o;
}

__global__ __launch_bounds__(256, 2) void mlp_kernel(
    const float* __restrict__ x, const bf16_t* __restrict__ wb,
    const float* __restrict__ bias, float* __restrict__ out)
{
    __shared__ __align__(16) bf16_t hs[2][TM][LDH];   // activations, double-buffered

    const int tid  = threadIdx.x;
    const int wave = tid >> 6;
    const int lane = tid & 63;
    const int c16  = lane & 15;        // A/B frag row index; C col (batch)
    const int quad = lane >> 4;        // k-group; C row group (neuron)
    const int m0 = (wave >> 1) * 64;   // neuron offset of wave quadrant
    const int n0 = (wave & 1) * 64;    // batch offset of wave quadrant
    const long rowbase = (long)blockIdx.x * TM;
    const int jb = m0 + quad * 4;      // neuron base for this lane (+ mi*16)

    // --- x in C-fragment layout: xr[mi][ni] = x[batch=n0+ni*16+c16][jb+mi*16 .. +3]
    floatx4 xr[4][4];
#pragma unroll
    for (int ni = 0; ni < 4; ++ni) {
        const float* xrow = x + (rowbase + n0 + ni*16 + c16) * HID;
#pragma unroll
        for (int mi = 0; mi < 4; ++mi)
            xr[mi][ni] = *(const floatx4*)&xrow[jb + mi*16];
    }
    // --- h0 = bf16(x) into hs[0]: 4 consecutive neurons per write => b64 writes
#pragma unroll
    for (int ni = 0; ni < 4; ++ni) {
        bf16_t* hrow = &hs[0][n0 + ni*16 + c16][0];
#pragma unroll
        for (int mi = 0; mi < 4; ++mi) {
            floatx4 v = xr[mi][ni];
            bf16x4 o = { (bf16_t)v[0], (bf16_t)v[1], (bf16_t)v[2], (bf16_t)v[3] };
            *(bf16x4*)&hrow[jb + mi*16] = o;
        }
    }

    // --- per-lane W fragment base: A row = m0+mi*16+c16, cols k*32+quad*8 .. +7
    const bf16_t* wl = wb + (m0 + c16) * HID + quad * 8;

    // --- prefetch layer-0 A-frags straight from global (L1/L2-hot)
    bf16x8 af[4][4];   // [mi][k]
#pragma unroll
    for (int mi = 0; mi < 4; ++mi)
#pragma unroll
      for (int k = 0; k < 4; ++k)
        af[mi][k] = *(const bf16x8*)&wl[mi*16*HID + k*32];

    // --- bias frags (prefetched one layer ahead)
    floatx4 bnext[4];
#pragma unroll
    for (int mi = 0; mi < 4; ++mi) bnext[mi] = *(const floatx4*)&bias[jb + mi*16];

    __syncthreads();   // hs[0] visible

#pragma unroll
    for (int l = 0; l < NLAYERS; ++l) {
        const int cur = l & 1;

        // acc init = bias (before bnext is overwritten by the prefetch)
        floatx4 acc[4][4];
#pragma unroll
        for (int mi = 0; mi < 4; ++mi)
#pragma unroll
          for (int ni = 0; ni < 4; ++ni)
            acc[mi][ni] = bnext[mi];

        if (l + 1 < NLAYERS) {
#pragma unroll
            for (int mi = 0; mi < 4; ++mi)
                bnext[mi] = *(const floatx4*)&bias[(l+1)*HID + jb + mi*16];
        }

        // K = 128 in 4 steps of 32; af[*][k] reloaded for layer l+1 right
        // after its last use so the global load overlaps remaining compute.
        const bf16_t* wnext = wl + (l + 1) * HID * HID;
#pragma unroll
        for (int k = 0; k < 4; ++k) {
            const int kc = k*32 + quad*8;
            bf16x8 bfr[4];
#pragma unroll
            for (int ni = 0; ni < 4; ++ni)
                bfr[ni] = *(const bf16x8*)&hs[cur][n0 + ni*16 + c16][kc];  // B = h
#pragma unroll
            for (int mi = 0; mi < 4; ++mi)
#pragma unroll
              for (int ni = 0; ni < 4; ++ni)
                acc[mi][ni] = __builtin_amdgcn_mfma_f32_16x16x32_bf16(
                                  af[mi][k], bfr[ni], acc[mi][ni], 0, 0, 0);
            if (l + 1 < NLAYERS) {
#pragma unroll
                for (int mi = 0; mi < 4; ++mi)
                    af[mi][k] = *(const bf16x8*)&wnext[mi*16*HID + k*32];
            }
        }

        if (l < NLAYERS - 1) {
            // h' = relu(acc) (+x for l>0), packed b64 writes into the OTHER buffer
#pragma unroll
            for (int ni = 0; ni < 4; ++ni) {
                bf16_t* hrow = &hs[cur ^ 1][n0 + ni*16 + c16][0];
#pragma unroll
                for (int mi = 0; mi < 4; ++mi) {
                    floatx4 v = acc[mi][ni];
                    float s0 = fmaxf(v[0], 0.0f), s1 = fmaxf(v[1], 0.0f);
                    float s2 = fmaxf(v[2], 0.0f), s3 = fmaxf(v[3], 0.0f);
                    if (l > 0) {
                        floatx4 xv = xr[mi][ni];
                        s0 += xv[0]; s1 += xv[1]; s2 += xv[2]; s3 += xv[3];
                    }
                    bf16x4 o = { (bf16_t)s0, (bf16_t)s1, (bf16_t)s2, (bf16_t)s3 };
                    *(bf16x4*)&hrow[jb + mi*16] = o;
                }
            }
            __syncthreads();   // hs[cur^1] staged for layer l+1
        } else {
            // last layer: relu + skip, fp32 dwordx4 stores
#pragma unroll
            for (int ni = 0; ni < 4; ++ni) {
                float* orow = out + (rowbase + n0 + ni*16 + c16) * HID;
#pragma unroll
                for (int mi = 0; mi < 4; ++mi) {
                    floatx4 v = acc[mi][ni];
                    floatx4 xv = xr[mi][ni];
                    floatx4 o;
                    o[0] = fmaxf(v[0], 0.0f) + xv[0];
                    o[1] = fmaxf(v[1], 0.0f) + xv[1];
                    o[2] = fmaxf(v[2], 0.0f) + xv[2];
                    o[3] = fmaxf(v[3], 0.0f) + xv[3];
                    *(floatx4*)&orow[jb + mi*16] = o;
                }
            }
        }
    }
}

extern "C" void kernel_launch(void* const* d_in, const int* in_sizes, int n_in,
                              void* d_out, int out_size, void* d_ws, size_t ws_size,
                              hipStream_t stream) {
    const float* x = (const float*)d_in[0];    // 262144*128
    const float* w = (const float*)d_in[1];    // 8*128*128
    const float* b = (const float*)d_in[2];    // 8*128
    float* out = (float*)d_out;
    bf16_t* wb = (bf16_t*)d_ws;                // 131072 bf16 = 256 KB scratch

    wconv_kernel<<<NLAYERS*HID*HID/(256*4), 256, 0, stream>>>(w, wb);

    const int nblocks = 262144 / TM;           // 2048
    mlp_kernel<<<nblocks, 256, 0, stream>>>(x, wb, b, out);
}